// Round 8
// baseline (53.015 us; speedup 1.0000x reference)
//
#include <hip/hip_runtime.h>
#include <math.h>

typedef __attribute__((ext_vector_type(8))) _Float16 f16x8;
typedef __attribute__((ext_vector_type(2))) _Float16 f16x2;
typedef __attribute__((ext_vector_type(4))) float f32x4;

// ============================ MFMA fused kernel v6 ============================
// v6 vs v5 (53 µs): K-ordering is now IH-MAJOR (step s' = ih*6 + c) so the 6
// feature fragments produced by one eval batch are consumed in 6 CONSECUTIVE
// MFMA steps. v5's c-major order gave every fragment a whole-loop live range;
// the compiler chose to rematerialize feats6 per use (VGPR_Count=92 proved it),
// costing 6x redundant VALU (~28us measured vs ~8us ideal). Short live ranges
// make keeping fragments in registers the obviously-cheap option.
// W layout changed to match (kan_combine_w kt' = ih*6+c).

#define TPB 256
#define BM  128
#define HSTRIDE 272                    // 128 cols x 2B + 16B pad
#define LDS_TOT (128 * HSTRIDE)        // 34816 B

__global__ __launch_bounds__(TPB, 2) void kan_mfma_kernel(
    const float* __restrict__ x, const _Float16* __restrict__ W0t,
    const _Float16* __restrict__ W1t, float* __restrict__ out)
{
    __shared__ char smem[LDS_TOT];
    const int tid  = threadIdx.x;
    const int lane = tid & 63;
    const int wid  = tid >> 6;          // 4 waves, disjoint 32-row strips
    const int gq   = lane >> 4;         // k-group 0..3
    const int lm   = lane & 15;
    const int wavebase = wid * 32;
    const long rowbase = (long)blockIdx.x * BM;

    // --- basis table -> piecewise-linear consts (computed per thread, exact) ---
    float FS0[5], FB0[5], FS1[5], FB1[5];
    {
        float bvv[3][5];
        #pragma unroll
        for (int g = 0; g < 3; ++g) {
            float gv = (float)g - 1.0f;
            float e[5]; float s = 0.f;
            #pragma unroll
            for (int i = 0; i < 5; ++i) {
                float cc = -0.8125f + 0.325f * (float)i;   // (knots[i+1]+knots[i+2])/2
                float d  = (gv - cc) * (1.0f / 0.65f);     // width 0.65
                e[i] = __expf(-d * d); s += e[i];
            }
            float inv = 1.0f / (s + 1e-6f);
            #pragma unroll
            for (int i = 0; i < 5; ++i) bvv[g][i] = e[i] * inv;
        }
        #pragma unroll
        for (int c = 0; c < 5; ++c) {
            FS0[c] = bvv[1][c] - bvv[0][c];  FB0[c] = bvv[0][c];
            FS1[c] = bvv[2][c] - bvv[1][c];  FB1[c] = 2.f * bvv[1][c] - bvv[2][c];
        }
    }

    auto feats6 = [&](float v, float* f) {
        float sg = 1.0f / (1.0f + __expf(-v));
        f[0] = v * sg;
        float gi = fminf(fmaxf(v, -1.f), 1.f) + 1.f;   // [0,2]
        bool s1 = gi >= 1.0f;
        #pragma unroll
        for (int c = 0; c < 5; ++c)
            f[c + 1] = fmaf(gi, s1 ? FS1[c] : FS0[c], s1 ? FB1[c] : FB0[c]);
    };

#if __has_builtin(__builtin_amdgcn_cvt_pkrtz)
    auto pk2 = [](float a, float b) -> f16x2 {
        return (f16x2)__builtin_amdgcn_cvt_pkrtz(a, b);
    };
#else
    auto pk2 = [](float a, float b) -> f16x2 {
        return f16x2{(_Float16)a, (_Float16)b};
    };
#endif

    // build all 6 feature fragments for 8 values (pairwise, packed via cvt_pk)
    auto buildFeats = [&](const float* v, f16x8* dst) {
        union U { f16x8 v8; f16x2 h2[4]; } u[6];
        #pragma unroll
        for (int q = 0; q < 4; ++q) {
            float fa[6], fb[6];
            feats6(v[2 * q], fa);
            feats6(v[2 * q + 1], fb);
            #pragma unroll
            for (int c = 0; c < 6; ++c) u[c].h2[q] = pk2(fa[c], fb[c]);
        }
        #pragma unroll
        for (int c = 0; c < 6; ++c) dst[c] = u[c].v8;
    };

    // ---------------- load x values for both i-halves ----------------
    float v0[2][8], v1[2][8];           // [mi][e] for ih=0 (i=gq*8..) / ih=1 (i=32+gq*8..)
    #pragma unroll
    for (int mi = 0; mi < 2; ++mi) {
        const float* xp = x + (rowbase + wavebase + mi * 16 + lm) * 64 + gq * 8;
        float4 a0 = *(const float4*)(xp);
        float4 a1 = *(const float4*)(xp + 4);
        float4 a2 = *(const float4*)(xp + 32);
        float4 a3 = *(const float4*)(xp + 36);
        v0[mi][0]=a0.x; v0[mi][1]=a0.y; v0[mi][2]=a0.z; v0[mi][3]=a0.w;
        v0[mi][4]=a1.x; v0[mi][5]=a1.y; v0[mi][6]=a1.z; v0[mi][7]=a1.w;
        v1[mi][0]=a2.x; v1[mi][1]=a2.y; v1[mi][2]=a2.z; v1[mi][3]=a2.w;
        v1[mi][4]=a3.x; v1[mi][5]=a3.y; v1[mi][6]=a3.z; v1[mi][7]=a3.w;
    }

    // ---------------- layer 0: h[32 rows/wave][128 cols], 12 ih-major steps ----------------
    f32x4 acc[2][8] = {};
    {
        const char* w0 = (const char*)W0t + gq * 2048 + lm * 16;
        f16x8 b0[8], b1[8];
        #pragma unroll
        for (int nf = 0; nf < 8; ++nf) b0[nf] = *(const f16x8*)(w0 + nf * 256);

        f16x8 fr[2][6];                  // live only across 6 consecutive steps
        buildFeats(v0[0], fr[0]);
        buildFeats(v0[1], fr[1]);

#define L0_STEP(S, C, CUR, NXT) do {                                          \
        if ((S) < 11) {                                                       \
            _Pragma("unroll")                                                 \
            for (int nf = 0; nf < 8; ++nf)                                    \
                NXT[nf] = *(const f16x8*)(w0 + ((S) + 1) * 8192 + nf * 256);  \
        }                                                                     \
        _Pragma("unroll")                                                     \
        for (int mi = 0; mi < 2; ++mi) {                                      \
            f16x8 a = fr[mi][C];                                              \
            _Pragma("unroll")                                                 \
            for (int nf = 0; nf < 8; ++nf)                                    \
                acc[mi][nf] = __builtin_amdgcn_mfma_f32_16x16x32_f16(         \
                    a, CUR[nf], acc[mi][nf], 0, 0, 0);                        \
        }                                                                     \
    } while (0)

        L0_STEP(0, 0, b0, b1); L0_STEP(1, 1, b1, b0);
        L0_STEP(2, 2, b0, b1); L0_STEP(3, 3, b1, b0);
        L0_STEP(4, 4, b0, b1); L0_STEP(5, 5, b1, b0);
        buildFeats(v1[0], fr[0]);
        buildFeats(v1[1], fr[1]);
        L0_STEP(6, 0, b0, b1); L0_STEP(7, 1, b1, b0);
        L0_STEP(8, 2, b0, b1); L0_STEP(9, 3, b1, b0);
        L0_STEP(10,4, b0, b1); L0_STEP(11,5, b1, b0);
#undef L0_STEP
    }

    // h -> H LDS f16 (C/D layout: row = gq*4+rg, col = nf*16+lm)
    #pragma unroll
    for (int mi = 0; mi < 2; ++mi)
        #pragma unroll
        for (int nf = 0; nf < 8; ++nf)
            #pragma unroll
            for (int rg = 0; rg < 4; ++rg)
                *(_Float16*)(smem + (wavebase + mi * 16 + gq * 4 + rg) * HSTRIDE
                             + (nf * 16 + lm) * 2) = (_Float16)acc[mi][nf][rg];
    __syncthreads();

    // ---------------- layer 1: out[32/wave][64], 2 halves x 12 ih-major steps ----------------
    f32x4 accO[2][4] = {};
    #pragma unroll
    for (int half = 0; half < 2; ++half) {
        float hv0[2][8], hv1[2][8];
        #pragma unroll
        for (int mi = 0; mi < 2; ++mi) {
            const char* hrow = smem + (wavebase + mi * 16 + lm) * HSTRIDE;
            f16x8 ha = *(const f16x8*)(hrow + (half * 64 + gq * 8) * 2);
            f16x8 hb = *(const f16x8*)(hrow + (half * 64 + 32 + gq * 8) * 2);
            #pragma unroll
            for (int e = 0; e < 8; ++e) { hv0[mi][e] = (float)ha[e]; hv1[mi][e] = (float)hb[e]; }
        }

        const char* w1 = (const char*)W1t + half * 49152 + gq * 1024 + lm * 16;
        f16x8 c0[4], c1[4];
        #pragma unroll
        for (int nf = 0; nf < 4; ++nf) c0[nf] = *(const f16x8*)(w1 + nf * 256);

        f16x8 fr[2][6];
        buildFeats(hv0[0], fr[0]);
        buildFeats(hv0[1], fr[1]);

#define L1_STEP(S, C, CUR, NXT) do {                                          \
        if ((S) < 11) {                                                       \
            _Pragma("unroll")                                                 \
            for (int nf = 0; nf < 4; ++nf)                                    \
                NXT[nf] = *(const f16x8*)(w1 + ((S) + 1) * 4096 + nf * 256);  \
        }                                                                     \
        _Pragma("unroll")                                                     \
        for (int mi = 0; mi < 2; ++mi) {                                      \
            f16x8 a = fr[mi][C];                                              \
            _Pragma("unroll")                                                 \
            for (int nf = 0; nf < 4; ++nf)                                    \
                accO[mi][nf] = __builtin_amdgcn_mfma_f32_16x16x32_f16(        \
                    a, CUR[nf], accO[mi][nf], 0, 0, 0);                       \
        }                                                                     \
    } while (0)

        L1_STEP(0, 0, c0, c1); L1_STEP(1, 1, c1, c0);
        L1_STEP(2, 2, c0, c1); L1_STEP(3, 3, c1, c0);
        L1_STEP(4, 4, c0, c1); L1_STEP(5, 5, c1, c0);
        buildFeats(hv1[0], fr[0]);
        buildFeats(hv1[1], fr[1]);
        L1_STEP(6, 0, c0, c1); L1_STEP(7, 1, c1, c0);
        L1_STEP(8, 2, c0, c1); L1_STEP(9, 3, c1, c0);
        L1_STEP(10,4, c0, c1); L1_STEP(11,5, c1, c0);
#undef L1_STEP
    }

    // ---------------- store out ----------------
    float* og = out + (rowbase + wavebase) * 64;
    #pragma unroll
    for (int mi = 0; mi < 2; ++mi)
        #pragma unroll
        for (int nf = 0; nf < 4; ++nf)
            #pragma unroll
            for (int rg = 0; rg < 4; ++rg)
                og[(mi * 16 + gq * 4 + rg) * 64 + nf * 16 + lm] = accO[mi][nf][rg];
}

// ------------- pre-kernel: combine imp/bw/sw/cp -> tiled f16 weights -------------
// IH-MAJOR chunk order: kt' = ih*6 + c, ih in {0,1}, c in {0..5}.
// W0t flat f = ((kt'*4+g)*128 + n)*8 + e ; i = ih*32 + g*8 + e ; edge = i*128+n
// W1t flat f = (((half*12+kt')*4+g)*64 + n)*8 + e ; i2 = half*64 + ih*32 + g*8 + e
__global__ __launch_bounds__(256) void kan_combine_w(
    const float* __restrict__ cp0, const float* __restrict__ bw0,
    const float* __restrict__ sw0, const float* __restrict__ imp0,
    const float* __restrict__ cp1, const float* __restrict__ bw1,
    const float* __restrict__ sw1, const float* __restrict__ imp1,
    _Float16* __restrict__ W0t, _Float16* __restrict__ W1t)
{
    int f = blockIdx.x * 256 + threadIdx.x;
    if (f < 49152) {
        int e = f & 7, n = (f >> 3) & 127, g = (f >> 10) & 3, kt = f >> 12;
        int ih = kt / 6, c = kt - ih * 6;
        int i = ih * 32 + g * 8 + e;
        int edge = i * 128 + n;
        float w = imp0[edge] * ((c == 0) ? bw0[edge] : sw0[edge] * cp0[edge * 5 + (c - 1)]);
        W0t[f] = (_Float16)w;
    } else {
        int f2 = f - 49152;
        int e = f2 & 7, n = (f2 >> 3) & 63, g = (f2 >> 9) & 3;
        int q = f2 >> 11;                 // 0..23
        int half = q / 12, kt = q - half * 12;
        int ih = kt / 6, c = kt - ih * 6;
        int i2 = half * 64 + ih * 32 + g * 8 + e;
        int edge = i2 * 64 + n;
        float w = imp1[edge] * ((c == 0) ? bw1[edge] : sw1[edge] * cp1[edge * 5 + (c - 1)]);
        W1t[f2] = (_Float16)w;
    }
}

// ===================== fallback: proven fp32 kernel (round 2) =====================
#define NTHR 256
#define JT 32
#define WS8 8

#define STAGE_L0(JBASE) do {                                                  \
    _Pragma("unroll")                                                         \
    for (int p = 0; p < 8; ++p) {                                             \
        int idx = tid + p * NTHR;                                             \
        int i  = idx >> 5;                                                    \
        int jj = idx & 31;                                                    \
        int e  = i * 128 + (JBASE) + jj;                                      \
        float im = imp0[e];                                                   \
        float wb = bw0[e] * im;                                               \
        float ws = sw0[e] * im;                                               \
        const float* cp = cp0 + e * 5;                                        \
        float* wp = wbuf + idx * WS8;                                         \
        wp[0] = wb;                                                           \
        wp[1] = ws * cp[0]; wp[2] = ws * cp[1]; wp[3] = ws * cp[2];           \
        wp[4] = ws * cp[3]; wp[5] = ws * cp[4];                               \
    }                                                                         \
} while (0)

#define STAGE_L1(IBASE, JBASE) do {                                           \
    _Pragma("unroll")                                                         \
    for (int p = 0; p < 8; ++p) {                                             \
        int idx = tid + p * NTHR;                                             \
        int ii = idx >> 5;                                                    \
        int jj = idx & 31;                                                    \
        int e  = ((IBASE) + ii) * 64 + (JBASE) + jj;                          \
        float im = imp1[e];                                                   \
        float wb = bw1[e] * im;                                               \
        float ws = sw1[e] * im;                                               \
        const float* cp = cp1 + e * 5;                                        \
        float* wp = wbuf + idx * WS8;                                         \
        wp[0] = wb;                                                           \
        wp[1] = ws * cp[0]; wp[2] = ws * cp[1]; wp[3] = ws * cp[2];           \
        wp[4] = ws * cp[3]; wp[5] = ws * cp[4];                               \
    }                                                                         \
} while (0)

#define COMPUTE_TILE(ACC) do {                                                \
    _Pragma("unroll 2")                                                       \
    for (int i = 0; i < 64; ++i) {                                            \
        float v  = vbuf[i][tid];                                              \
        float sg = 1.0f / (1.0f + __expf(-v));                                \
        float base = v * sg;                                                  \
        float xc = fminf(fmaxf(v, -1.0f), 1.0f);                              \
        float gi = xc + 1.0f;                                                 \
        int lo = (int)gi; lo = (lo > 2) ? 2 : lo;                             \
        float fr = gi - (float)lo;                                            \
        int hi = (fr > 0.0f) ? (lo + 1) : lo;                                 \
        float b0 = bvt[lo][0]; b0 += (bvt[hi][0] - b0) * fr;                  \
        float b1 = bvt[lo][1]; b1 += (bvt[hi][1] - b1) * fr;                  \
        float b2 = bvt[lo][2]; b2 += (bvt[hi][2] - b2) * fr;                  \
        float b3 = bvt[lo][3]; b3 += (bvt[hi][3] - b3) * fr;                  \
        float b4 = bvt[lo][4]; b4 += (bvt[hi][4] - b4) * fr;                  \
        const float* wr = wbuf + i * (JT * WS8);                              \
        _Pragma("unroll")                                                     \
        for (int jj = 0; jj < JT; ++jj) {                                     \
            const float* wp = wr + jj * WS8;                                  \
            float a = ACC[jj];                                                \
            a = fmaf(wp[0], base, a);                                         \
            a = fmaf(wp[1], b0, a);                                           \
            a = fmaf(wp[2], b1, a);                                           \
            a = fmaf(wp[3], b2, a);                                           \
            a = fmaf(wp[4], b3, a);                                           \
            a = fmaf(wp[5], b4, a);                                           \
            ACC[jj] = a;                                                      \
        }                                                                     \
    }                                                                         \
} while (0)

__global__ __launch_bounds__(NTHR) void kan_fused_kernel(
    const float* __restrict__ x,
    const float* __restrict__ cp0, const float* __restrict__ bw0,
    const float* __restrict__ sw0, const float* __restrict__ imp0,
    const float* __restrict__ cp1, const float* __restrict__ bw1,
    const float* __restrict__ sw1, const float* __restrict__ imp1,
    float* __restrict__ out)
{
    __shared__ float vbuf[64][NTHR + 1];
    __shared__ float wbuf[64 * JT * WS8];
    __shared__ float bvt[3][8];

    const int tid = threadIdx.x;

    if (tid < 3) {
        float gv = -1.0f + (float)tid;
        float e[5];
        float s = 0.0f;
        #pragma unroll
        for (int i = 0; i < 5; ++i) {
            float c = -0.8125f + 0.325f * (float)i;
            float d = (gv - c) * (1.0f / 0.65f);
            e[i] = expf(-d * d);
            s += e[i];
        }
        float inv = 1.0f / (s + 1e-6f);
        #pragma unroll
        for (int i = 0; i < 5; ++i) bvt[tid][i] = e[i] * inv;
    }

    {
        const float4* xg = (const float4*)(x + (size_t)blockIdx.x * (NTHR * 64));
        #pragma unroll
        for (int it = 0; it < 16; ++it) {
            int e4 = tid + it * NTHR;
            float4 v = xg[e4];
            int r  = e4 >> 4;
            int ib = (e4 & 15) << 2;
            vbuf[ib + 0][r] = v.x;
            vbuf[ib + 1][r] = v.y;
            vbuf[ib + 2][r] = v.z;
            vbuf[ib + 3][r] = v.w;
        }
    }
    __syncthreads();

    float h0[32] = {}, h1[32] = {}, h2[32] = {}, h3[32] = {};
    STAGE_L0(0);   __syncthreads(); COMPUTE_TILE(h0); __syncthreads();
    STAGE_L0(32);  __syncthreads(); COMPUTE_TILE(h1); __syncthreads();
    STAGE_L0(64);  __syncthreads(); COMPUTE_TILE(h2); __syncthreads();
    STAGE_L0(96);  __syncthreads(); COMPUTE_TILE(h3); __syncthreads();

    #pragma unroll
    for (int i = 0; i < 32; ++i) vbuf[i][tid] = h0[i];
    #pragma unroll
    for (int i = 0; i < 32; ++i) vbuf[32 + i][tid] = h1[i];

    float o0[32] = {}, o1[32] = {};
    STAGE_L1(0, 0);   __syncthreads(); COMPUTE_TILE(o0); __syncthreads();
    STAGE_L1(0, 32);  __syncthreads(); COMPUTE_TILE(o1); __syncthreads();

    #pragma unroll
    for (int i = 0; i < 32; ++i) vbuf[i][tid] = h2[i];
    #pragma unroll
    for (int i = 0; i < 32; ++i) vbuf[32 + i][tid] = h3[i];

    STAGE_L1(64, 0);  __syncthreads(); COMPUTE_TILE(o0); __syncthreads();
    STAGE_L1(64, 32); __syncthreads(); COMPUTE_TILE(o1);

    float4* og = (float4*)(out + (size_t)blockIdx.x * (NTHR * 64) + (size_t)tid * 64);
    #pragma unroll
    for (int q = 0; q < 8; ++q)
        og[q] = make_float4(o0[4 * q + 0], o0[4 * q + 1], o0[4 * q + 2], o0[4 * q + 3]);
    #pragma unroll
    for (int q = 0; q < 8; ++q)
        og[8 + q] = make_float4(o1[4 * q + 0], o1[4 * q + 1], o1[4 * q + 2], o1[4 * q + 3]);
}

// =================================== launch ===================================
extern "C" void kernel_launch(void* const* d_in, const int* in_sizes, int n_in,
                              void* d_out, int out_size, void* d_ws, size_t ws_size,
                              hipStream_t stream) {
    const float* x    = (const float*)d_in[0];
    const float* cp0  = (const float*)d_in[1];
    const float* bw0  = (const float*)d_in[2];
    const float* sw0  = (const float*)d_in[3];
    const float* imp0 = (const float*)d_in[4];
    const float* cp1  = (const float*)d_in[5];
    const float* bw1  = (const float*)d_in[6];
    const float* sw1  = (const float*)d_in[7];
    const float* imp1 = (const float*)d_in[8];
    float* out = (float*)d_out;

    const int B = in_sizes[0] / 64;                 // 131072
    const size_t need = 98304 * sizeof(_Float16);   // 192 KB combined weights

    if (ws_size >= need && (B % BM) == 0) {
        _Float16* W0t = (_Float16*)d_ws;
        _Float16* W1t = W0t + 49152;
        kan_combine_w<<<384, 256, 0, stream>>>(cp0, bw0, sw0, imp0,
                                               cp1, bw1, sw1, imp1, W0t, W1t);
        kan_mfma_kernel<<<B / BM, TPB, 0, stream>>>(x, W0t, W1t, out);
    } else {
        kan_fused_kernel<<<B / NTHR, NTHR, 0, stream>>>(
            x, cp0, bw0, sw0, imp0, cp1, bw1, sw1, imp1, out);
    }
}

// Round 9
// 39.665 us; speedup vs baseline: 1.3366x; 1.3366x over previous
//
#include <hip/hip_runtime.h>
#include <math.h>

typedef __attribute__((ext_vector_type(8))) _Float16 f16x8;
typedef __attribute__((ext_vector_type(2))) _Float16 f16x2;
typedef __attribute__((ext_vector_type(4))) float f32x4;

// ============================ MFMA fused kernel v7 ============================
// v7 vs v6 (53 µs): ALGEBRAIC COLLAPSE of the basis features. With G=3, each
// basis_c(gi) is piecewise-linear in gi (breakpoint gi=1), so
//   sum_c cp[c]*basis_c(gi) = (P0+Q0*gi) + s1*((P1-P0)+(Q1-Q0)*gi),  s1=[gi>=1]
// with P/Q folded per-edge into W by kan_combine_w (fp32, then one f16 round).
// Feature vector per value: {silu(v), 1, gi, s1, s1*gi} -> K=5*64=320 (was 384):
// MFMA & B-stream -17%, feature VALU ~3x cheaper (kills the remat tax v5/v6
// couldn't shake). Everything else (strips, H path, b dbuf) unchanged from v6.

#define TPB 256
#define BM  128
#define HSTRIDE 272                    // 128 cols x 2B + 16B pad
#define LDS_TOT (128 * HSTRIDE)        // 34816 B

__global__ __launch_bounds__(TPB, 2) void kan_mfma_kernel(
    const float* __restrict__ x, const _Float16* __restrict__ W0t,
    const _Float16* __restrict__ W1t, float* __restrict__ out)
{
    __shared__ char smem[LDS_TOT];
    const int tid  = threadIdx.x;
    const int lane = tid & 63;
    const int wid  = tid >> 6;          // 4 waves, disjoint 32-row strips
    const int gq   = lane >> 4;         // k-group 0..3
    const int lm   = lane & 15;
    const int wavebase = wid * 32;
    const long rowbase = (long)blockIdx.x * BM;

#if __has_builtin(__builtin_amdgcn_cvt_pkrtz)
    auto pk2 = [](float a, float b) -> f16x2 {
        return (f16x2)__builtin_amdgcn_cvt_pkrtz(a, b);
    };
#else
    auto pk2 = [](float a, float b) -> f16x2 {
        return f16x2{(_Float16)a, (_Float16)b};
    };
#endif
#if __has_builtin(__builtin_amdgcn_rcpf)
    auto frcp = [](float a) -> float { return __builtin_amdgcn_rcpf(a); };
#else
    auto frcp = [](float a) -> float { return 1.0f / a; };
#endif

    const _Float16 o1h = (_Float16)1.0f;
    const f16x8 ones = {o1h, o1h, o1h, o1h, o1h, o1h, o1h, o1h};

    // features for 8 values -> 5 fragments {base, 1, gi, s1, s1*gi}
    auto buildFeats5 = [&](const float* v, f16x8* dst) {
        union U { f16x8 v8; f16x2 h2[4]; } u0, u2, u3, u4;
        #pragma unroll
        for (int q = 0; q < 4; ++q) {
            float va = v[2 * q], vb = v[2 * q + 1];
            float ba = va * frcp(1.0f + __expf(-va));
            float bb = vb * frcp(1.0f + __expf(-vb));
            float ga = fminf(fmaxf(va, -1.f), 1.f) + 1.f;   // [0,2]
            float gb = fminf(fmaxf(vb, -1.f), 1.f) + 1.f;
            float s1a = (ga >= 1.f) ? 1.f : 0.f;
            float s1b = (gb >= 1.f) ? 1.f : 0.f;
            float sga = (ga >= 1.f) ? ga : 0.f;
            float sgb = (gb >= 1.f) ? gb : 0.f;
            u0.h2[q] = pk2(ba, bb);
            u2.h2[q] = pk2(ga, gb);
            u3.h2[q] = pk2(s1a, s1b);
            u4.h2[q] = pk2(sga, sgb);
        }
        dst[0] = u0.v8; dst[1] = ones; dst[2] = u2.v8; dst[3] = u3.v8; dst[4] = u4.v8;
    };

    // ---------------- load x values for both i-halves ----------------
    float v0[2][8], v1[2][8];           // [mi][e]: ih=0 (i=gq*8..), ih=1 (i=32+gq*8..)
    #pragma unroll
    for (int mi = 0; mi < 2; ++mi) {
        const float* xp = x + (rowbase + wavebase + mi * 16 + lm) * 64 + gq * 8;
        float4 a0 = *(const float4*)(xp);
        float4 a1 = *(const float4*)(xp + 4);
        float4 a2 = *(const float4*)(xp + 32);
        float4 a3 = *(const float4*)(xp + 36);
        v0[mi][0]=a0.x; v0[mi][1]=a0.y; v0[mi][2]=a0.z; v0[mi][3]=a0.w;
        v0[mi][4]=a1.x; v0[mi][5]=a1.y; v0[mi][6]=a1.z; v0[mi][7]=a1.w;
        v1[mi][0]=a2.x; v1[mi][1]=a2.y; v1[mi][2]=a2.z; v1[mi][3]=a2.w;
        v1[mi][4]=a3.x; v1[mi][5]=a3.y; v1[mi][6]=a3.z; v1[mi][7]=a3.w;
    }

    // ---------------- layer 0: h[32 rows/wave][128 cols], 10 ih-major steps ----------------
    f32x4 acc[2][8] = {};
    {
        const char* w0 = (const char*)W0t + gq * 2048 + lm * 16;
        f16x8 b0[8], b1[8];
        #pragma unroll
        for (int nf = 0; nf < 8; ++nf) b0[nf] = *(const f16x8*)(w0 + nf * 256);

        f16x8 fr[2][5];
        buildFeats5(v0[0], fr[0]);
        buildFeats5(v0[1], fr[1]);

#define L0_STEP(S, C, CUR, NXT) do {                                          \
        if ((S) < 9) {                                                        \
            _Pragma("unroll")                                                 \
            for (int nf = 0; nf < 8; ++nf)                                    \
                NXT[nf] = *(const f16x8*)(w0 + ((S) + 1) * 8192 + nf * 256);  \
        }                                                                     \
        _Pragma("unroll")                                                     \
        for (int mi = 0; mi < 2; ++mi) {                                      \
            f16x8 a = fr[mi][C];                                              \
            _Pragma("unroll")                                                 \
            for (int nf = 0; nf < 8; ++nf)                                    \
                acc[mi][nf] = __builtin_amdgcn_mfma_f32_16x16x32_f16(         \
                    a, CUR[nf], acc[mi][nf], 0, 0, 0);                        \
        }                                                                     \
    } while (0)

        L0_STEP(0, 0, b0, b1); L0_STEP(1, 1, b1, b0);
        L0_STEP(2, 2, b0, b1); L0_STEP(3, 3, b1, b0);
        L0_STEP(4, 4, b0, b1);
        buildFeats5(v1[0], fr[0]);
        buildFeats5(v1[1], fr[1]);
        L0_STEP(5, 0, b1, b0); L0_STEP(6, 1, b0, b1);
        L0_STEP(7, 2, b1, b0); L0_STEP(8, 3, b0, b1);
        L0_STEP(9, 4, b1, b0);
#undef L0_STEP
    }

    // h -> H LDS f16 (C/D layout: row = gq*4+rg, col = nf*16+lm)
    #pragma unroll
    for (int mi = 0; mi < 2; ++mi)
        #pragma unroll
        for (int nf = 0; nf < 8; ++nf)
            #pragma unroll
            for (int rg = 0; rg < 4; ++rg)
                *(_Float16*)(smem + (wavebase + mi * 16 + gq * 4 + rg) * HSTRIDE
                             + (nf * 16 + lm) * 2) = (_Float16)acc[mi][nf][rg];
    __syncthreads();

    // ---------------- layer 1: out[32/wave][64], 2 halves x 10 ih-major steps ----------------
    f32x4 accO[2][4] = {};
    #pragma unroll
    for (int half = 0; half < 2; ++half) {
        float hv0[2][8], hv1[2][8];
        #pragma unroll
        for (int mi = 0; mi < 2; ++mi) {
            const char* hrow = smem + (wavebase + mi * 16 + lm) * HSTRIDE;
            f16x8 ha = *(const f16x8*)(hrow + (half * 64 + gq * 8) * 2);
            f16x8 hb = *(const f16x8*)(hrow + (half * 64 + 32 + gq * 8) * 2);
            #pragma unroll
            for (int e = 0; e < 8; ++e) { hv0[mi][e] = (float)ha[e]; hv1[mi][e] = (float)hb[e]; }
        }

        const char* w1 = (const char*)W1t + half * 40960 + gq * 1024 + lm * 16;
        f16x8 c0[4], c1[4];
        #pragma unroll
        for (int nf = 0; nf < 4; ++nf) c0[nf] = *(const f16x8*)(w1 + nf * 256);

        f16x8 fr[2][5];
        buildFeats5(hv0[0], fr[0]);
        buildFeats5(hv0[1], fr[1]);

#define L1_STEP(S, C, CUR, NXT) do {                                          \
        if ((S) < 9) {                                                        \
            _Pragma("unroll")                                                 \
            for (int nf = 0; nf < 4; ++nf)                                    \
                NXT[nf] = *(const f16x8*)(w1 + ((S) + 1) * 4096 + nf * 256);  \
        }                                                                     \
        _Pragma("unroll")                                                     \
        for (int mi = 0; mi < 2; ++mi) {                                      \
            f16x8 a = fr[mi][C];                                              \
            _Pragma("unroll")                                                 \
            for (int nf = 0; nf < 4; ++nf)                                    \
                accO[mi][nf] = __builtin_amdgcn_mfma_f32_16x16x32_f16(        \
                    a, CUR[nf], accO[mi][nf], 0, 0, 0);                       \
        }                                                                     \
    } while (0)

        L1_STEP(0, 0, c0, c1); L1_STEP(1, 1, c1, c0);
        L1_STEP(2, 2, c0, c1); L1_STEP(3, 3, c1, c0);
        L1_STEP(4, 4, c0, c1);
        buildFeats5(hv1[0], fr[0]);
        buildFeats5(hv1[1], fr[1]);
        L1_STEP(5, 0, c1, c0); L1_STEP(6, 1, c0, c1);
        L1_STEP(7, 2, c1, c0); L1_STEP(8, 3, c0, c1);
        L1_STEP(9, 4, c1, c0);
#undef L1_STEP
    }

    // ---------------- store out ----------------
    float* og = out + (rowbase + wavebase) * 64;
    #pragma unroll
    for (int mi = 0; mi < 2; ++mi)
        #pragma unroll
        for (int nf = 0; nf < 4; ++nf)
            #pragma unroll
            for (int rg = 0; rg < 4; ++rg)
                og[(mi * 16 + gq * 4 + rg) * 64 + nf * 16 + lm] = accO[mi][nf][rg];
}

// ------------- pre-kernel: fold imp/bw/sw/cp + basis table -> f16 weights -------------
// Feature order q: {base, 1, gi, s1, s1*gi}. Per edge:
//   P0 = sum_c cp*bv0 ; Q0 = sum_c cp*(bv1-bv0) ; P1 = sum_c cp*(2bv1-bv2) ;
//   Q1 = sum_c cp*(bv2-bv1);  w[q] = imp * {bw, sw*P0, sw*Q0, sw*(P1-P0), sw*(Q1-Q0)}
// W0t flat f = ((s*4+g)*128+n)*8+e ; s=ih*5+q ; i = ih*32+g*8+e ; edge = i*128+n
// W1t flat f = (((half*10+s)*4+g)*64+n)*8+e ; i2 = half*64+ih*32+g*8+e
__global__ __launch_bounds__(256) void kan_combine_w(
    const float* __restrict__ cp0, const float* __restrict__ bw0,
    const float* __restrict__ sw0, const float* __restrict__ imp0,
    const float* __restrict__ cp1, const float* __restrict__ bw1,
    const float* __restrict__ sw1, const float* __restrict__ imp1,
    _Float16* __restrict__ W0t, _Float16* __restrict__ W1t)
{
    // basis table (exact reference construction)
    float bvv[3][5];
    #pragma unroll
    for (int g = 0; g < 3; ++g) {
        float gv = (float)g - 1.0f;
        float e[5]; float s = 0.f;
        #pragma unroll
        for (int i = 0; i < 5; ++i) {
            float cc = -0.8125f + 0.325f * (float)i;
            float d  = (gv - cc) * (1.0f / 0.65f);
            e[i] = __expf(-d * d); s += e[i];
        }
        float inv = 1.0f / (s + 1e-6f);
        #pragma unroll
        for (int i = 0; i < 5; ++i) bvv[g][i] = e[i] * inv;
    }

    auto wval = [&](const float* cp, float bw, float sw, float imp, int q) -> float {
        if (q == 0) return imp * bw;
        float P0 = 0.f, Q0 = 0.f, P1 = 0.f, Q1 = 0.f;
        #pragma unroll
        for (int c = 0; c < 5; ++c) {
            P0 += cp[c] * bvv[0][c];
            Q0 += cp[c] * (bvv[1][c] - bvv[0][c]);
            P1 += cp[c] * (2.f * bvv[1][c] - bvv[2][c]);
            Q1 += cp[c] * (bvv[2][c] - bvv[1][c]);
        }
        float r = (q == 1) ? P0 : (q == 2) ? Q0 : (q == 3) ? (P1 - P0) : (Q1 - Q0);
        return imp * sw * r;
    };

    int f = blockIdx.x * 256 + threadIdx.x;
    if (f < 40960) {
        int e = f & 7, n = (f >> 3) & 127, g = (f >> 10) & 3, s = f >> 12; // s 0..9
        int ih = s / 5, q = s - ih * 5;
        int i = ih * 32 + g * 8 + e;
        int edge = i * 128 + n;
        W0t[f] = (_Float16)wval(cp0 + edge * 5, bw0[edge], sw0[edge], imp0[edge], q);
    } else if (f < 81920) {
        int f2 = f - 40960;
        int e = f2 & 7, n = (f2 >> 3) & 63, g = (f2 >> 9) & 3;
        int t = f2 >> 11;                 // 0..19
        int half = t / 10, s = t - half * 10;
        int ih = s / 5, q = s - ih * 5;
        int i2 = half * 64 + ih * 32 + g * 8 + e;
        int edge = i2 * 64 + n;
        W1t[f2] = (_Float16)wval(cp1 + edge * 5, bw1[edge], sw1[edge], imp1[edge], q);
    }
}

// ===================== fallback: proven fp32 kernel (round 2) =====================
#define NTHR 256
#define JT 32
#define WS8 8

#define STAGE_L0(JBASE) do {                                                  \
    _Pragma("unroll")                                                         \
    for (int p = 0; p < 8; ++p) {                                             \
        int idx = tid + p * NTHR;                                             \
        int i  = idx >> 5;                                                    \
        int jj = idx & 31;                                                    \
        int e  = i * 128 + (JBASE) + jj;                                      \
        float im = imp0[e];                                                   \
        float wb = bw0[e] * im;                                               \
        float ws = sw0[e] * im;                                               \
        const float* cp = cp0 + e * 5;                                        \
        float* wp = wbuf + idx * WS8;                                         \
        wp[0] = wb;                                                           \
        wp[1] = ws * cp[0]; wp[2] = ws * cp[1]; wp[3] = ws * cp[2];           \
        wp[4] = ws * cp[3]; wp[5] = ws * cp[4];                               \
    }                                                                         \
} while (0)

#define STAGE_L1(IBASE, JBASE) do {                                           \
    _Pragma("unroll")                                                         \
    for (int p = 0; p < 8; ++p) {                                             \
        int idx = tid + p * NTHR;                                             \
        int ii = idx >> 5;                                                    \
        int jj = idx & 31;                                                    \
        int e  = ((IBASE) + ii) * 64 + (JBASE) + jj;                          \
        float im = imp1[e];                                                   \
        float wb = bw1[e] * im;                                               \
        float ws = sw1[e] * im;                                               \
        const float* cp = cp1 + e * 5;                                        \
        float* wp = wbuf + idx * WS8;                                         \
        wp[0] = wb;                                                           \
        wp[1] = ws * cp[0]; wp[2] = ws * cp[1]; wp[3] = ws * cp[2];           \
        wp[4] = ws * cp[3]; wp[5] = ws * cp[4];                               \
    }                                                                         \
} while (0)

#define COMPUTE_TILE(ACC) do {                                                \
    _Pragma("unroll 2")                                                       \
    for (int i = 0; i < 64; ++i) {                                            \
        float v  = vbuf[i][tid];                                              \
        float sg = 1.0f / (1.0f + __expf(-v));                                \
        float base = v * sg;                                                  \
        float xc = fminf(fmaxf(v, -1.0f), 1.0f);                              \
        float gi = xc + 1.0f;                                                 \
        int lo = (int)gi; lo = (lo > 2) ? 2 : lo;                             \
        float fr = gi - (float)lo;                                            \
        int hi = (fr > 0.0f) ? (lo + 1) : lo;                                 \
        float b0 = bvt[lo][0]; b0 += (bvt[hi][0] - b0) * fr;                  \
        float b1 = bvt[lo][1]; b1 += (bvt[hi][1] - b1) * fr;                  \
        float b2 = bvt[lo][2]; b2 += (bvt[hi][2] - b2) * fr;                  \
        float b3 = bvt[lo][3]; b3 += (bvt[hi][3] - b3) * fr;                  \
        float b4 = bvt[lo][4]; b4 += (bvt[hi][4] - b4) * fr;                  \
        const float* wr = wbuf + i * (JT * WS8);                              \
        _Pragma("unroll")                                                     \
        for (int jj = 0; jj < JT; ++jj) {                                     \
            const float* wp = wr + jj * WS8;                                  \
            float a = ACC[jj];                                                \
            a = fmaf(wp[0], base, a);                                         \
            a = fmaf(wp[1], b0, a);                                           \
            a = fmaf(wp[2], b1, a);                                           \
            a = fmaf(wp[3], b2, a);                                           \
            a = fmaf(wp[4], b3, a);                                           \
            a = fmaf(wp[5], b4, a);                                           \
            ACC[jj] = a;                                                      \
        }                                                                     \
    }                                                                         \
} while (0)

__global__ __launch_bounds__(NTHR) void kan_fused_kernel(
    const float* __restrict__ x,
    const float* __restrict__ cp0, const float* __restrict__ bw0,
    const float* __restrict__ sw0, const float* __restrict__ imp0,
    const float* __restrict__ cp1, const float* __restrict__ bw1,
    const float* __restrict__ sw1, const float* __restrict__ imp1,
    float* __restrict__ out)
{
    __shared__ float vbuf[64][NTHR + 1];
    __shared__ float wbuf[64 * JT * WS8];
    __shared__ float bvt[3][8];

    const int tid = threadIdx.x;

    if (tid < 3) {
        float gv = -1.0f + (float)tid;
        float e[5];
        float s = 0.0f;
        #pragma unroll
        for (int i = 0; i < 5; ++i) {
            float c = -0.8125f + 0.325f * (float)i;
            float d = (gv - c) * (1.0f / 0.65f);
            e[i] = expf(-d * d);
            s += e[i];
        }
        float inv = 1.0f / (s + 1e-6f);
        #pragma unroll
        for (int i = 0; i < 5; ++i) bvt[tid][i] = e[i] * inv;
    }

    {
        const float4* xg = (const float4*)(x + (size_t)blockIdx.x * (NTHR * 64));
        #pragma unroll
        for (int it = 0; it < 16; ++it) {
            int e4 = tid + it * NTHR;
            float4 v = xg[e4];
            int r  = e4 >> 4;
            int ib = (e4 & 15) << 2;
            vbuf[ib + 0][r] = v.x;
            vbuf[ib + 1][r] = v.y;
            vbuf[ib + 2][r] = v.z;
            vbuf[ib + 3][r] = v.w;
        }
    }
    __syncthreads();

    float h0[32] = {}, h1[32] = {}, h2[32] = {}, h3[32] = {};
    STAGE_L0(0);   __syncthreads(); COMPUTE_TILE(h0); __syncthreads();
    STAGE_L0(32);  __syncthreads(); COMPUTE_TILE(h1); __syncthreads();
    STAGE_L0(64);  __syncthreads(); COMPUTE_TILE(h2); __syncthreads();
    STAGE_L0(96);  __syncthreads(); COMPUTE_TILE(h3); __syncthreads();

    #pragma unroll
    for (int i = 0; i < 32; ++i) vbuf[i][tid] = h0[i];
    #pragma unroll
    for (int i = 0; i < 32; ++i) vbuf[32 + i][tid] = h1[i];

    float o0[32] = {}, o1[32] = {};
    STAGE_L1(0, 0);   __syncthreads(); COMPUTE_TILE(o0); __syncthreads();
    STAGE_L1(0, 32);  __syncthreads(); COMPUTE_TILE(o1); __syncthreads();

    #pragma unroll
    for (int i = 0; i < 32; ++i) vbuf[i][tid] = h2[i];
    #pragma unroll
    for (int i = 0; i < 32; ++i) vbuf[32 + i][tid] = h3[i];

    STAGE_L1(64, 0);  __syncthreads(); COMPUTE_TILE(o0); __syncthreads();
    STAGE_L1(64, 32); __syncthreads(); COMPUTE_TILE(o1);

    float4* og = (float4*)(out + (size_t)blockIdx.x * (NTHR * 64) + (size_t)tid * 64);
    #pragma unroll
    for (int q = 0; q < 8; ++q)
        og[q] = make_float4(o0[4 * q + 0], o0[4 * q + 1], o0[4 * q + 2], o0[4 * q + 3]);
    #pragma unroll
    for (int q = 0; q < 8; ++q)
        og[8 + q] = make_float4(o1[4 * q + 0], o1[4 * q + 1], o1[4 * q + 2], o1[4 * q + 3]);
}

// =================================== launch ===================================
extern "C" void kernel_launch(void* const* d_in, const int* in_sizes, int n_in,
                              void* d_out, int out_size, void* d_ws, size_t ws_size,
                              hipStream_t stream) {
    const float* x    = (const float*)d_in[0];
    const float* cp0  = (const float*)d_in[1];
    const float* bw0  = (const float*)d_in[2];
    const float* sw0  = (const float*)d_in[3];
    const float* imp0 = (const float*)d_in[4];
    const float* cp1  = (const float*)d_in[5];
    const float* bw1  = (const float*)d_in[6];
    const float* sw1  = (const float*)d_in[7];
    const float* imp1 = (const float*)d_in[8];
    float* out = (float*)d_out;

    const int B = in_sizes[0] / 64;                 // 131072
    const size_t need = 81920 * sizeof(_Float16);   // 160 KB folded weights

    if (ws_size >= need && (B % BM) == 0) {
        _Float16* W0t = (_Float16*)d_ws;
        _Float16* W1t = W0t + 40960;
        kan_combine_w<<<320, 256, 0, stream>>>(cp0, bw0, sw0, imp0,
                                               cp1, bw1, sw1, imp1, W0t, W1t);
        kan_mfma_kernel<<<B / BM, TPB, 0, stream>>>(x, W0t, W1t, out);
    } else {
        kan_fused_kernel<<<B / NTHR, NTHR, 0, stream>>>(
            x, cp0, bw0, sw0, imp0, cp1, bw1, sw1, imp1, out);
    }
}